// Round 4
// baseline (139.047 us; speedup 1.0000x reference)
//
#include <hip/hip_runtime.h>
#include <hip/hip_bf16.h>
#include <stdint.h>

#define B_ 64
#define S_ 512
#define I_ 256
#define H_ 1024
#define O_ 128
#define M_ (B_*S_)   // 32768

typedef float f32x4 __attribute__((ext_vector_type(4)));
typedef unsigned short u16x4 __attribute__((ext_vector_type(4)));
typedef unsigned short u16x8 __attribute__((ext_vector_type(8)));

__device__ __forceinline__ unsigned short f2bf(float f) {
    unsigned u = __float_as_uint(f);
    u += 0x7FFFu + ((u >> 16) & 1u);
    return (unsigned short)(u >> 16);
}
__device__ __forceinline__ float bf2f(unsigned short s) {
    return __uint_as_float((unsigned)s << 16);
}

// ---- K0: fp32 -> fp8 e4m3, emitted in PER-LANE FRAGMENT order:
//   region[tile][kq][rb][lane*8B], lane l: row = rb*16 + (l&15),
//   k = kq*32 + (l>>4)*8 .. +8.  kf then loads fragments as straight
//   global_load_dwordx2 at base + lane*8 (512B contiguous per wave inst).
// Each thread produces 16B = lanes (l0, l0+1): same quad, rows r and r+1.
__global__ void __launch_bounds__(256) k0_convert(
    const float* __restrict__ x, const float* __restrict__ Win,
    uint8_t* __restrict__ xf8, uint8_t* __restrict__ wf8,
    unsigned* __restrict__ firstCross, unsigned* __restrict__ cnt)
{
    const unsigned tid = blockIdx.x * 256 + threadIdx.x;   // 540672 total
    const float* src;
    uint8_t* dst;
    if (tid < 524288u) {          // x: 256 tiles
        unsigned T   = tid >> 11;
        unsigned rem = (tid << 4) & 32767u;
        unsigned kq  = rem >> 12;
        unsigned rb  = (rem >> 9) & 7u;
        unsigned l0  = (rem >> 3) & 63u;   // even
        src = x + ((size_t)(T * 128 + rb * 16 + (l0 & 15u))) * 256
                + kq * 32 + (l0 >> 4) * 8;
        dst = xf8 + ((size_t)tid << 4);
    } else {                      // W_in: 8 tiles (= hn slices)
        unsigned t2  = tid - 524288u;
        unsigned T   = t2 >> 11;
        unsigned rem = (t2 << 4) & 32767u;
        unsigned kq  = rem >> 12;
        unsigned rb  = (rem >> 9) & 7u;
        unsigned l0  = (rem >> 3) & 63u;
        src = Win + ((size_t)(T * 128 + rb * 16 + (l0 & 15u))) * 256
                  + kq * 32 + (l0 >> 4) * 8;
        dst = wf8 + ((size_t)t2 << 4);
    }
    float4 a = *(const float4*)src;
    float4 b = *(const float4*)(src + 4);
    float4 c = *(const float4*)(src + 256);   // next row, same k
    float4 e = *(const float4*)(src + 260);
    int w0 = 0, w1 = 0, w2 = 0, w3 = 0;
    w0 = __builtin_amdgcn_cvt_pk_fp8_f32(a.x, a.y, w0, false);
    w0 = __builtin_amdgcn_cvt_pk_fp8_f32(a.z, a.w, w0, true);
    w1 = __builtin_amdgcn_cvt_pk_fp8_f32(b.x, b.y, w1, false);
    w1 = __builtin_amdgcn_cvt_pk_fp8_f32(b.z, b.w, w1, true);
    w2 = __builtin_amdgcn_cvt_pk_fp8_f32(c.x, c.y, w2, false);
    w2 = __builtin_amdgcn_cvt_pk_fp8_f32(c.z, c.w, w2, true);
    w3 = __builtin_amdgcn_cvt_pk_fp8_f32(e.x, e.y, w3, false);
    w3 = __builtin_amdgcn_cvt_pk_fp8_f32(e.z, e.w, w3, true);
    int4 o; o.x = w0; o.y = w1; o.z = w2; o.w = w3;
    *(int4*)dst = o;
    if (blockIdx.x == 0) {
        if (threadIdx.x < 64) firstCross[threadIdx.x] = 0xFFFFFFFFu;
        else if (threadIdx.x < 128) cnt[threadIdx.x - 64] = 0u;
    }
}

// ---- KF: fp8 GEMM straight from global fragments (no LDS staging, no
// barriers in the K loop) + speculative scan + last-block-per-b output.
// B fragments register-resident for the whole block (32 x 8B = 64 VGPRs).
__global__ void __launch_bounds__(256, 3) kf_gemm_scan(
    const uint8_t* __restrict__ xf8, const uint8_t* __restrict__ wf8,
    const float* __restrict__ b_in, const float* __restrict__ b_rec,
    const float* __restrict__ tau_m, const float* __restrict__ tau_n,
    const float* __restrict__ b_out,
    unsigned* __restrict__ firstCross, unsigned* __restrict__ cnt,
    float* __restrict__ out)
{
    __shared__ uint8_t lsbuf[32768];   // lS only: [t-granule8][h]*bf16x? dump+scan
    __shared__ int lastFlag;

    const int tid  = threadIdx.x;
    const int w    = tid >> 6;
    const int lane = tid & 63;
    const int idx  = blockIdx.x;
    const int b    = (idx & 7) | ((idx >> 6) << 3);   // XCD swizzle
    const int hn   = (idx >> 3) & 7;
    const int wave_m = (w >> 1) * 64;   // t-half
    const int wave_n = (w & 1) * 64;    // h-half
    const int colrow = lane & 15;
    const int quad   = lane >> 4;

    // scan state (threads 0..127 own one h column each)
    float alpha = 0.f, beta = 0.f, cbr = 0.f, oma = 0.f, ombr = 0.f;
    float d = 0.f, mem = 0.f;
    unsigned cross = 0xFFFFFFFFu;
    if (tid < 128) {
        const int hs = hn * 128 + tid;
        alpha = 1.f / (1.f + expf(-tau_m[hs]));
        beta  = 1.f / (1.f + expf(-tau_n[hs]));
        oma = 1.f - alpha; ombr = 1.f - beta;
        cbr = ombr * (b_in[hs] + b_rec[hs]);
    }

    // B fragments: cached in registers across all 4 t-tiles
    const uint8_t* wB = wf8 + (size_t)hn * 32768 + ((wave_n >> 4) << 9) + lane * 8;
    long long bq[32];
#pragma unroll
    for (int kq = 0; kq < 8; ++kq)
#pragma unroll
        for (int ni = 0; ni < 4; ++ni)
            bq[kq * 4 + ni] = *(const long long*)(wB + (size_t)(kq * 8 + ni) * 512);

    for (int tt = 0; tt < 4; ++tt) {
        const uint8_t* xA = xf8 + (size_t)(b * 4 + tt) * 32768
                          + ((wave_m >> 4) << 9) + lane * 8;

        f32x4 acc[4][4];
#pragma unroll
        for (int mi = 0; mi < 4; ++mi)
#pragma unroll
            for (int ni = 0; ni < 4; ++ni)
                acc[mi][ni] = (f32x4){0.f, 0.f, 0.f, 0.f};

#pragma unroll
        for (int kq = 0; kq < 8; ++kq) {
            long long a[4];
#pragma unroll
            for (int mi = 0; mi < 4; ++mi)
                a[mi] = *(const long long*)(xA + (size_t)(kq * 8 + mi) * 512);
#pragma unroll
            for (int mi = 0; mi < 4; ++mi)
#pragma unroll
                for (int ni = 0; ni < 4; ++ni)
                    acc[mi][ni] = __builtin_amdgcn_mfma_f32_16x16x32_fp8_fp8(
                        a[mi], bq[kq * 4 + ni], acc[mi][ni], 0, 0, 0);
        }

        __syncthreads();   // prior tile's scan readers done with lS

        // dump tile -> lS[t-granule][h] bf16
#pragma unroll
        for (int mi = 0; mi < 4; ++mi) {
            const int t0 = wave_m + mi * 16 + quad * 4;
            const int gbase = (t0 >> 3) * 2048 + ((t0 & 4) << 1);
#pragma unroll
            for (int ni = 0; ni < 4; ++ni) {
                const int h0 = wave_n + ni * 16 + colrow;
                u16x4 p;
                p[0] = f2bf(acc[mi][ni][0]);
                p[1] = f2bf(acc[mi][ni][1]);
                p[2] = f2bf(acc[mi][ni][2]);
                p[3] = f2bf(acc[mi][ni][3]);
                *(u16x4*)(lsbuf + gbase + (h0 << 4)) = p;
            }
        }
        __syncthreads();

        if (tid < 128) {
            const uint8_t* rowp = lsbuf + tid * 16;
            for (int tl0 = 0; tl0 < 128; tl0 += 16) {
                const int gb = (tl0 >> 3) * 2048;
                u16x8 v0 = *(const u16x8*)(rowp + gb);
                u16x8 v1 = *(const u16x8*)(rowp + gb + 2048);
                float f[16];
#pragma unroll
                for (int u = 0; u < 8; ++u) { f[u] = bf2f(v0[u]); f[8 + u] = bf2f(v1[u]); }
#pragma unroll
                for (int u = 0; u < 16; ++u) {
                    d   = fmaf(beta,  d,   fmaf(ombr, f[u], cbr));
                    mem = fmaf(alpha, mem, oma * d);
                    if (mem > 1.0f) {
                        unsigned ts = (unsigned)(tt * 128 + tl0 + u);
                        if (ts < cross) cross = ts;
                    }
                }
            }
        }
    }

    if (tid < 128 && cross != 0xFFFFFFFFu) atomicMin(firstCross + b, cross);
    __syncthreads();
    if (tid == 0) {
        __threadfence();                       // publish atomicMins (release)
        unsigned old = atomicAdd(cnt + b, 1u);
        int flag = 0;
        if (old == 7u) {                       // last of the 8 blocks for b
            __threadfence();                   // acquire
            unsigned fc = atomicAdd(firstCross + b, 0u);  // device-scope read
            flag = (fc == 0xFFFFFFFFu) ? 1 : 0;
        }
        lastFlag = flag;
    }
    __syncthreads();
    if (lastFlag) {                            // block-uniform: no spikes in b
        float* sg = (float*)lsbuf;
        if (tid < 128) sg[tid] = 1.f / (1.f + expf(-b_out[tid]));
        __syncthreads();
        const int q = tid & 31;
        float4 v = *(float4*)(sg + q * 4);
        float* obase = out + (size_t)b * (S_ * O_) + q * 4;
        const int trow = tid >> 5;
#pragma unroll 4
        for (int k = 0; k < 64; ++k)
            *(float4*)(obase + (size_t)(trow + k * 8) * O_) = v;
    }
}

// ---- K3: exact repair + output for spiking batches (runs ~never) ----------
__global__ void __launch_bounds__(1024) k3_repair(
    const float* __restrict__ x, const float* __restrict__ W_in,
    const float* __restrict__ b_in,
    const float* __restrict__ W_rec, const float* __restrict__ b_rec,
    const float* __restrict__ tau_m, const float* __restrict__ tau_n,
    const float* __restrict__ W_out, const float* __restrict__ b_out,
    const unsigned* __restrict__ firstCross,
    unsigned long long* __restrict__ gmask,
    float* __restrict__ out)
{
    const int b = blockIdx.x;
    if (firstCross[b] == 0xFFFFFFFFu) return;   // block-uniform
    const int h = threadIdx.x;
    __shared__ float xrow[I_];
    __shared__ unsigned long long msk[16];
    if (h < 16) msk[h] = 0ull;
    const float alpha = 1.f / (1.f + expf(-tau_m[h]));
    const float beta  = 1.f / (1.f + expf(-tau_n[h]));
    const float bsum  = b_in[h] + b_rec[h];
    const float* wi = W_in + (size_t)h * I_;
    const float* wr = W_rec + (size_t)h * H_;
    float d = 0.f, mem = 0.f;
    for (int t = 0; t < S_; ++t) {
        __syncthreads();
        if (h < I_) xrow[h] = x[((size_t)b * S_ + t) * I_ + h];
        __syncthreads();
        float ffv = 0.f;
        for (int k = 0; k < I_; ++k) ffv += xrow[k] * wi[k];
        float rec = 0.f;
#pragma unroll
        for (int wd = 0; wd < 16; ++wd) {
            unsigned long long mw = msk[wd];
            while (mw) {
                int bit = __ffsll((long long)mw) - 1;
                rec += wr[(wd << 6) + bit];
                mw &= (mw - 1);
            }
        }
        float tot = ffv + bsum + rec;
        d   = beta  * d   + (1.f - beta)  * tot;
        mem = alpha * mem + (1.f - alpha) * d;
        int sp = (mem > 1.0f) ? 1 : 0;
        if (sp) mem = 0.f;
        unsigned long long bal = __ballot(sp);
        __syncthreads();
        if ((h & 63) == 0) {
            msk[h >> 6] = bal;
            gmask[((size_t)b * S_ + t) * 16 + (h >> 6)] = bal;
        }
    }
    __syncthreads();
    __threadfence_block();
    // phase 2: outputs for this batch (rare path, simplicity over speed)
    for (int i = h; i < S_ * O_; i += 1024) {
        const int t = i >> 7, o = i & (O_ - 1);
        float logit = b_out[o];
        const unsigned long long* m = gmask + ((size_t)b * S_ + t) * 16;
        const float* wo = W_out + (size_t)o * H_;
        for (int wd = 0; wd < 16; ++wd) {
            unsigned long long mw = m[wd];
            while (mw) {
                int bit = __ffsll((long long)mw) - 1;
                logit += wo[(wd << 6) + bit];
                mw &= (mw - 1);
            }
        }
        out[((size_t)b * S_ + t) * O_ + o] = 1.f / (1.f + expf(-logit));
    }
}

extern "C" void kernel_launch(void* const* d_in, const int* in_sizes, int n_in,
                              void* d_out, int out_size, void* d_ws, size_t ws_size,
                              hipStream_t stream) {
    const float* x     = (const float*)d_in[0];
    const float* W_in  = (const float*)d_in[1];
    const float* b_in  = (const float*)d_in[2];
    const float* W_rec = (const float*)d_in[3];
    const float* b_rec = (const float*)d_in[4];
    const float* tau_m = (const float*)d_in[5];
    const float* tau_n = (const float*)d_in[6];
    const float* W_out = (const float*)d_in[7];
    const float* b_out = (const float*)d_in[8];
    float* out = (float*)d_out;

    char* ws = (char*)d_ws;
    size_t off = 0;
    uint8_t* xf8 = (uint8_t*)(ws + off);               off += (size_t)M_ * I_;        // 8 MB
    uint8_t* wf8 = (uint8_t*)(ws + off);               off += (size_t)H_ * I_;        // 256 KB
    unsigned long long* gmask = (unsigned long long*)(ws + off); off += (size_t)B_ * S_ * 16 * 8; // 4 MB
    unsigned* firstCross = (unsigned*)(ws + off);      off += 256;
    unsigned* cnt = (unsigned*)(ws + off);             off += 256;
    if (ws_size < off) return;

    k0_convert<<<2112, 256, 0, stream>>>(x, W_in, xf8, wf8, firstCross, cnt);
    kf_gemm_scan<<<512, 256, 0, stream>>>(xf8, wf8, b_in, b_rec, tau_m, tau_n,
                                          b_out, firstCross, cnt, out);
    k3_repair<<<64, 1024, 0, stream>>>(x, W_in, b_in, W_rec, b_rec, tau_m, tau_n,
                                       W_out, b_out, firstCross, gmask, out);
}

// Round 5
// 136.516 us; speedup vs baseline: 1.0185x; 1.0185x over previous
//
#include <hip/hip_runtime.h>
#include <hip/hip_bf16.h>
#include <stdint.h>

#define B_ 64
#define S_ 512
#define I_ 256
#define H_ 1024
#define O_ 128
#define M_ (B_*S_)   // 32768

typedef float f32x4 __attribute__((ext_vector_type(4)));
typedef unsigned short u16x4 __attribute__((ext_vector_type(4)));
typedef unsigned short u16x8 __attribute__((ext_vector_type(8)));

__device__ __forceinline__ unsigned short f2bf(float f) {
    unsigned u = __float_as_uint(f);
    u += 0x7FFFu + ((u >> 16) & 1u);
    return (unsigned short)(u >> 16);
}
__device__ __forceinline__ float bf2f(unsigned short s) {
    return __uint_as_float((unsigned)s << 16);
}

// ---- K0: fp32 -> fp8 e4m3 into per-lane fragment order, via LDS transpose.
// A region: [tile128][kq(8)][rb(8)][lane*8B]  (tile = 128 t-rows, 32 KB)
// B region: [hn16(16)][kq(8)][rb(4)][lane*8B] (tile = 64 h-rows, 16 KB)
// Fragment semantics: lane l holds row rb*16+(l&15), k = kq*32+(l>>4)*8..+8.
// Each k0 block: 64 source rows. Reads 1KB/wave contiguous, writes 1KB/wave
// contiguous; LDS (stride-65 u32) decouples the two orders.
__global__ void __launch_bounds__(256) k0_convert(
    const float* __restrict__ x, const float* __restrict__ Win,
    uint8_t* __restrict__ xf8, uint8_t* __restrict__ wf8,
    unsigned* __restrict__ firstCross)
{
    __shared__ unsigned lds32[64 * 65];   // 16.6 KB
    const int i = blockIdx.x;             // 0..511 x-blocks, 512..527 W-blocks
    const int t = threadIdx.x;

    const float* src;
    uint8_t* dstBase;
    int kqStride;
    if (i < 512) {
        const int r0 = i * 64;                  // global x row
        src = x + (size_t)r0 * 256;
        const int T = i >> 1;                   // 128-row tile
        const int rbase = (i & 1) * 4;          // rb offset (0 or 4)
        dstBase = xf8 + (size_t)T * 32768 + rbase * 512;
        kqStride = 4096;
    } else {
        const int i2 = i - 512;
        src = Win + (size_t)(i2 * 64) * 256;
        dstBase = wf8 + (size_t)i2 * 16384;
        kqStride = 2048;
    }

    // read phase: 64 rows x 256 floats, wave reads one full 1KB row per inst
#pragma unroll
    for (int j = 0; j < 16; ++j) {
        const int f = j * 256 + t;          // float4 index
        const int lrow = f >> 6, c4 = f & 63;
        float4 v = *(const float4*)(src + (size_t)lrow * 256 + c4 * 4);
        int w0 = 0;
        w0 = __builtin_amdgcn_cvt_pk_fp8_f32(v.x, v.y, w0, false);
        w0 = __builtin_amdgcn_cvt_pk_fp8_f32(v.z, v.w, w0, true);
        lds32[lrow * 65 + c4] = (unsigned)w0;
    }
    __syncthreads();

    // write phase: 1024 x 16B chunks in fragment order, contiguous per wave
#pragma unroll
    for (int j = 0; j < 4; ++j) {
        const int c = j * 256 + t;          // 16B chunk index
        const int kq  = c >> 7;
        const int rem = c & 127;
        const int rbl = rem >> 5;           // 0..3 local 16-row group
        const int l0  = (rem & 31) * 2;     // even lane
        const int r   = l0 & 15;
        const int q   = l0 >> 4;            // k-chunk 0..3
        const int lrow = rbl * 16 + r;
        const int c0 = kq * 8 + q * 2;
        uint4 o;
        o.x = lds32[lrow * 65 + c0];
        o.y = lds32[lrow * 65 + c0 + 1];
        o.z = lds32[(lrow + 1) * 65 + c0];
        o.w = lds32[(lrow + 1) * 65 + c0 + 1];
        *(uint4*)(dstBase + kq * kqStride + rbl * 512 + l0 * 8) = o;
    }

    if (i == 0 && t < 64) firstCross[t] = 0xFFFFFFFFu;
}

// ---- KF: fp8 GEMM from global fragments + speculative scan ----------------
// 1024 blocks = (b 64) x (hn 16 tiles of 64 h). 4 blocks/CU, 16 waves/CU.
// Wave w owns t-band w*32..+31 (acc 2x4). B frags register-resident (16 KB
// slice -> 64 VGPRs). No staging LDS; lS (16 KB) only for dump+scan.
__global__ void __launch_bounds__(256, 4) kf_gemm_scan(
    const uint8_t* __restrict__ xf8, const uint8_t* __restrict__ wf8,
    const float* __restrict__ b_in, const float* __restrict__ b_rec,
    const float* __restrict__ tau_m, const float* __restrict__ tau_n,
    unsigned* __restrict__ firstCross)
{
    __shared__ uint8_t lsbuf[16384];   // [granule16][h64][8t] bf16

    const int tid  = threadIdx.x;
    const int w    = tid >> 6;
    const int lane = tid & 63;
    const int idx  = blockIdx.x;
    const int b    = (idx & 7) | ((idx >> 7) << 3);   // XCD swizzle
    const int hn   = (idx >> 3) & 15;
    const int colrow = lane & 15;
    const int quad   = lane >> 4;

    // scan state: threads 0..63 own one h column each
    float alpha = 0.f, beta = 0.f, cbr = 0.f, oma = 0.f, ombr = 0.f;
    float d = 0.f, mem = 0.f;
    unsigned cross = 0xFFFFFFFFu;
    if (tid < 64) {
        const int hs = hn * 64 + tid;
        alpha = 1.f / (1.f + expf(-tau_m[hs]));
        beta  = 1.f / (1.f + expf(-tau_n[hs]));
        oma = 1.f - alpha; ombr = 1.f - beta;
        cbr = ombr * (b_in[hs] + b_rec[hs]);
    }

    // B fragments, resident across all 4 t-tiles: 32 x 8B
    const uint8_t* wB = wf8 + (size_t)hn * 16384 + lane * 8;
    long long bq[32];
#pragma unroll
    for (int kq = 0; kq < 8; ++kq)
#pragma unroll
        for (int ni = 0; ni < 4; ++ni)
            bq[kq * 4 + ni] = *(const long long*)(wB + kq * 2048 + ni * 512);

    for (int tt = 0; tt < 4; ++tt) {
        const uint8_t* xA = xf8 + (size_t)(b * 4 + tt) * 32768
                          + w * 1024 + lane * 8;   // rb base = w*2

        f32x4 acc[2][4];
#pragma unroll
        for (int mi = 0; mi < 2; ++mi)
#pragma unroll
            for (int ni = 0; ni < 4; ++ni)
                acc[mi][ni] = (f32x4){0.f, 0.f, 0.f, 0.f};

#pragma unroll
        for (int kq = 0; kq < 8; ++kq) {
            long long a[2];
#pragma unroll
            for (int mi = 0; mi < 2; ++mi)
                a[mi] = *(const long long*)(xA + kq * 4096 + mi * 512);
#pragma unroll
            for (int mi = 0; mi < 2; ++mi)
#pragma unroll
                for (int ni = 0; ni < 4; ++ni)
                    acc[mi][ni] = __builtin_amdgcn_mfma_f32_16x16x32_fp8_fp8(
                        a[mi], bq[kq * 4 + ni], acc[mi][ni], 0, 0, 0);
        }

        __syncthreads();   // prior tile's scan readers done with lS

        // dump: wave w covers t = w*32 + mi*16 + quad*4 + r, h = ni*16+colrow
#pragma unroll
        for (int mi = 0; mi < 2; ++mi) {
            const int t0 = w * 32 + mi * 16 + quad * 4;
            const int gb = (t0 >> 3) * 1024 + (t0 & 7) * 2;
#pragma unroll
            for (int ni = 0; ni < 4; ++ni) {
                const int h0 = ni * 16 + colrow;
                u16x4 p;
                p[0] = f2bf(acc[mi][ni][0]);
                p[1] = f2bf(acc[mi][ni][1]);
                p[2] = f2bf(acc[mi][ni][2]);
                p[3] = f2bf(acc[mi][ni][3]);
                *(u16x4*)(lsbuf + gb + h0 * 16) = p;
            }
        }
        __syncthreads();

        if (tid < 64) {
            const uint8_t* rowp = lsbuf + tid * 16;
            for (int tl0 = 0; tl0 < 128; tl0 += 16) {
                const int gb = (tl0 >> 3) * 1024;
                u16x8 v0 = *(const u16x8*)(rowp + gb);
                u16x8 v1 = *(const u16x8*)(rowp + gb + 1024);
                float f[16];
#pragma unroll
                for (int u = 0; u < 8; ++u) { f[u] = bf2f(v0[u]); f[8 + u] = bf2f(v1[u]); }
#pragma unroll
                for (int u = 0; u < 16; ++u) {
                    d   = fmaf(beta,  d,   fmaf(ombr, f[u], cbr));
                    mem = fmaf(alpha, mem, oma * d);
                    if (mem > 1.0f) {
                        unsigned ts = (unsigned)(tt * 128 + tl0 + u);
                        if (ts < cross) cross = ts;
                    }
                }
            }
        }
    }

    if (tid < 64 && cross != 0xFFFFFFFFu) atomicMin(firstCross + b, cross);
}

// ---- K3: exact repair + output for spiking batches (runs ~never) ----------
__global__ void __launch_bounds__(1024) k3_repair(
    const float* __restrict__ x, const float* __restrict__ W_in,
    const float* __restrict__ b_in,
    const float* __restrict__ W_rec, const float* __restrict__ b_rec,
    const float* __restrict__ tau_m, const float* __restrict__ tau_n,
    const float* __restrict__ W_out, const float* __restrict__ b_out,
    const unsigned* __restrict__ firstCross,
    unsigned long long* __restrict__ gmask,
    float* __restrict__ out)
{
    const int b = blockIdx.x;
    if (firstCross[b] == 0xFFFFFFFFu) return;   // block-uniform
    const int h = threadIdx.x;
    __shared__ float xrow[I_];
    __shared__ unsigned long long msk[16];
    if (h < 16) msk[h] = 0ull;
    const float alpha = 1.f / (1.f + expf(-tau_m[h]));
    const float beta  = 1.f / (1.f + expf(-tau_n[h]));
    const float bsum  = b_in[h] + b_rec[h];
    const float* wi = W_in + (size_t)h * I_;
    const float* wr = W_rec + (size_t)h * H_;
    float d = 0.f, mem = 0.f;
    for (int t = 0; t < S_; ++t) {
        __syncthreads();
        if (h < I_) xrow[h] = x[((size_t)b * S_ + t) * I_ + h];
        __syncthreads();
        float ffv = 0.f;
        for (int k = 0; k < I_; ++k) ffv += xrow[k] * wi[k];
        float rec = 0.f;
#pragma unroll
        for (int wd = 0; wd < 16; ++wd) {
            unsigned long long mw = msk[wd];
            while (mw) {
                int bit = __ffsll((long long)mw) - 1;
                rec += wr[(wd << 6) + bit];
                mw &= (mw - 1);
            }
        }
        float tot = ffv + bsum + rec;
        d   = beta  * d   + (1.f - beta)  * tot;
        mem = alpha * mem + (1.f - alpha) * d;
        int sp = (mem > 1.0f) ? 1 : 0;
        if (sp) mem = 0.f;
        unsigned long long bal = __ballot(sp);
        __syncthreads();
        if ((h & 63) == 0) {
            msk[h >> 6] = bal;
            gmask[((size_t)b * S_ + t) * 16 + (h >> 6)] = bal;
        }
    }
    __syncthreads();
    __threadfence_block();
    // phase 2: outputs for this whole batch (rare path)
    for (int i = h; i < S_ * O_; i += 1024) {
        const int t = i >> 7, o = i & (O_ - 1);
        float logit = b_out[o];
        const unsigned long long* m = gmask + ((size_t)b * S_ + t) * 16;
        const float* wo = W_out + (size_t)o * H_;
        for (int wd = 0; wd < 16; ++wd) {
            unsigned long long mw = m[wd];
            while (mw) {
                int bit = __ffsll((long long)mw) - 1;
                logit += wo[(wd << 6) + bit];
                mw &= (mw - 1);
            }
        }
        out[((size_t)b * S_ + t) * O_ + o] = 1.f / (1.f + expf(-logit));
    }
}

// ---- K4: fast-path output for non-spiking batches (float4, full chip) -----
__global__ void __launch_bounds__(256) k4_out(
    const float* __restrict__ b_out,
    const unsigned* __restrict__ firstCross,
    float* __restrict__ out)
{
    const int i4 = blockIdx.x * 256 + threadIdx.x;   // float4 index
    const int b  = i4 >> 14;                         // 16384 float4 per batch
    if (firstCross[b] != 0xFFFFFFFFu) return;        // k3 owns this batch
    const int o4 = i4 & 31;
    float4 v = *(const float4*)(b_out + o4 * 4);
    float4 r;
    r.x = 1.f / (1.f + expf(-v.x));
    r.y = 1.f / (1.f + expf(-v.y));
    r.z = 1.f / (1.f + expf(-v.z));
    r.w = 1.f / (1.f + expf(-v.w));
    *(float4*)(out + (size_t)i4 * 4) = r;
}

extern "C" void kernel_launch(void* const* d_in, const int* in_sizes, int n_in,
                              void* d_out, int out_size, void* d_ws, size_t ws_size,
                              hipStream_t stream) {
    const float* x     = (const float*)d_in[0];
    const float* W_in  = (const float*)d_in[1];
    const float* b_in  = (const float*)d_in[2];
    const float* W_rec = (const float*)d_in[3];
    const float* b_rec = (const float*)d_in[4];
    const float* tau_m = (const float*)d_in[5];
    const float* tau_n = (const float*)d_in[6];
    const float* W_out = (const float*)d_in[7];
    const float* b_out = (const float*)d_in[8];
    float* out = (float*)d_out;

    char* ws = (char*)d_ws;
    size_t off = 0;
    uint8_t* xf8 = (uint8_t*)(ws + off);               off += (size_t)M_ * I_;        // 8 MB
    uint8_t* wf8 = (uint8_t*)(ws + off);               off += (size_t)H_ * I_;        // 256 KB
    unsigned long long* gmask = (unsigned long long*)(ws + off); off += (size_t)B_ * S_ * 16 * 8; // 4 MB
    unsigned* firstCross = (unsigned*)(ws + off);      off += 256;
    if (ws_size < off) return;

    k0_convert<<<528, 256, 0, stream>>>(x, W_in, xf8, wf8, firstCross);
    kf_gemm_scan<<<1024, 256, 0, stream>>>(xf8, wf8, b_in, b_rec, tau_m, tau_n,
                                           firstCross);
    k3_repair<<<64, 1024, 0, stream>>>(x, W_in, b_in, W_rec, b_rec, tau_m, tau_n,
                                       W_out, b_out, firstCross, gmask, out);
    k4_out<<<4096, 256, 0, stream>>>(b_out, firstCross, out);
}